// Round 2
// baseline (474.226 us; speedup 1.0000x reference)
//
#include <hip/hip_runtime.h>
#include <hip/hip_bf16.h>
#include <math.h>

#define B_ROWS 1024
#define V_COLS 50257
#define E_DIM  128
#define BM     128
#define BN     128
#define NNB    393                 // ceil(V_COLS / BN)
#define VPAD   (NNB * BN)          // 50304
#define N4     (V_COLS * E_DIM / 4)   // 1608224
#define N4P    (VPAD * E_DIM / 4)     // 1609728

typedef __attribute__((ext_vector_type(8))) short short8;
typedef __attribute__((ext_vector_type(4))) float floatx4;

static __device__ __forceinline__ unsigned short f2bf(float x) {
    union { float f; unsigned int u; } c; c.f = x;
    unsigned int u = c.u;
    unsigned int r = u + 0x7fffu + ((u >> 16) & 1u);
    return (unsigned short)(r >> 16);
}

// async global->LDS, 16B per lane; LDS dest = uniform base + lane*16 (linear),
// swizzle is applied on the per-lane GLOBAL address (m104/m173 pattern).
static __device__ __forceinline__ void gload16(const void* g, void* l) {
    __builtin_amdgcn_global_load_lds(
        (const __attribute__((address_space(1))) void*)g,
        (__attribute__((address_space(3))) void*)l,
        16, 0, 0);
}

// ---------------------------------------------------------------- find one-hot index
__global__ void find_idx_kernel(const float* __restrict__ xs, int* __restrict__ idx) {
    long i = (long)blockIdx.x * blockDim.x + threadIdx.x;
    const long n4 = (long)B_ROWS * V_COLS / 4;
    if (i >= n4) return;
    floatx4 v = __builtin_nontemporal_load((const floatx4*)xs + i);
    float vals[4] = {v.x, v.y, v.z, v.w};
    #pragma unroll
    for (int c = 0; c < 4; ++c) {
        if (vals[c] != 0.0f) {
            long f = 4 * i + c;
            int b = (int)(f / V_COLS);
            idx[b] = (int)(f - (long)b * V_COLS);
        }
    }
}

// ---------------------------------------------------------------- NEG fp32 -> bf16 (padded to VPAD rows, zeros)
__global__ void cvt_bf16_kernel(const float* __restrict__ src, ushort4* __restrict__ dst) {
    int i = blockIdx.x * blockDim.x + threadIdx.x;
    if (i >= N4P) return;
    ushort4 o;
    if (i < N4) {
        floatx4 v = __builtin_nontemporal_load((const floatx4*)src + i);
        o.x = f2bf(v.x); o.y = f2bf(v.y); o.z = f2bf(v.z); o.w = f2bf(v.w);
    } else {
        o.x = 0; o.y = 0; o.z = 0; o.w = 0;
    }
    dst[i] = o;
}

// ---------------------------------------------------------------- t[b] = EMBEDM[idx[b]] @ metric  (bf16 out)
__global__ void compute_t_kernel(const float* __restrict__ EMB, const float* __restrict__ metric,
                                 const int* __restrict__ idx, unsigned short* __restrict__ t) {
    __shared__ float erow[E_DIM];
    int b = blockIdx.x, tid = threadIdx.x;
    int id = idx[b];
    erow[tid] = EMB[(long)id * E_DIM + tid];
    __syncthreads();
    float acc = 0.f;
    #pragma unroll 16
    for (int k = 0; k < E_DIM; ++k) acc += erow[k] * metric[k * E_DIM + tid];
    t[b * E_DIM + tid] = f2bf(acc);
}

// ---------------------------------------------------------------- tiled MFMA GEMM: scores = t @ neg^T
// 128x128 block tile, 512 threads = 8 waves (2x4) -> 16 waves/CU at 2 blocks/CU.
// Staging: global_load_lds dwordx4, source-address XOR-swizzled, LDS linear.
// grid = (M-tiles=8, NNB): the 8 blocks sharing a B-tile are consecutive -> L2 hits.
template <bool WRITE_OUT>
__global__ __launch_bounds__(512, 4) void gemm_kernel(const unsigned short* __restrict__ t,
                                                      const unsigned short* __restrict__ neg,
                                                      float2* __restrict__ partials,
                                                      const float* __restrict__ lse,
                                                      float* __restrict__ out) {
    __shared__ __align__(16) unsigned char smem[128 * 132 * 4]; // 67584 B: tiles (64KB) then score buf
    __shared__ float2 stats[4][128];
    __shared__ float lsev[128];

    const int tid  = threadIdx.x;
    const int lane = tid & 63, wave = tid >> 6;
    const int l16  = lane & 15, q = lane >> 4;
    const int wm   = wave >> 2, wn = wave & 3;          // 2 x 4 wave grid, each wave 64x32
    const int mbase = blockIdx.x * BM;
    const int nbase = blockIdx.y * BN;

    if (WRITE_OUT && tid < 128) lsev[tid] = lse[mbase + tid];

    // ---- stage A (t rows) and B (neg rows) into LDS via async DMA
    uint4* ldsA = (uint4*)smem;
    uint4* ldsB = (uint4*)(smem + 32768);
    const uint4* srcA = (const uint4*)(t + (size_t)mbase * E_DIM);
    const uint4* srcB = (const uint4*)(neg + (size_t)nbase * E_DIM);
    // 2048 16B-chunks per tile; wave w covers [w*256, w*256+256), 4 issues of 64
    {
        const int p0 = wave * 256 + lane;
        #pragma unroll
        for (int i = 0; i < 4; ++i) {
            int p = p0 + i * 64;
            int r = p >> 4, c = p & 15;
            int s = (r << 4) + (c ^ (r & 15));       // pre-swizzled global chunk
            int pbase = wave * 256 + i * 64;          // wave-uniform LDS chunk base
            gload16(srcA + s, ldsA + pbase);
            gload16(srcB + s, ldsB + pbase);
        }
    }
    __syncthreads();

    // ---- MFMA: each wave computes 64x32 (4x2 frags of 16x16x32)
    floatx4 acc[4][2];
    #pragma unroll
    for (int i = 0; i < 4; ++i)
        #pragma unroll
        for (int j = 0; j < 2; ++j) acc[i][j] = (floatx4){0, 0, 0, 0};

    #pragma unroll
    for (int ks = 0; ks < 4; ++ks) {
        short8 af[4], bfr[2];
        #pragma unroll
        for (int mf = 0; mf < 4; ++mf) {
            int row = wm * 64 + mf * 16 + l16;
            af[mf] = *(const short8*)&ldsA[(row << 4) + ((ks * 4 + q) ^ (row & 15))];
        }
        #pragma unroll
        for (int nf = 0; nf < 2; ++nf) {
            int row = wn * 32 + nf * 16 + l16;
            bfr[nf] = *(const short8*)&ldsB[(row << 4) + ((ks * 4 + q) ^ (row & 15))];
        }
        #pragma unroll
        for (int mf = 0; mf < 4; ++mf)
            #pragma unroll
            for (int nf = 0; nf < 2; ++nf)
                acc[mf][nf] = __builtin_amdgcn_mfma_f32_16x16x32_bf16(af[mf], bfr[nf], acc[mf][nf], 0, 0, 0);
    }

    // acc[mf][nf][r] is score at m-row = wm*64+mf*16+q*4+r, col = nbase+wn*32+nf*16+l16

    if (!WRITE_OUT) {
        // ---- per-row (max, sumexp) over this block's 128 cols
        const bool v0 = (nbase + wn * 32 + l16) < V_COLS;
        const bool v1 = (nbase + wn * 32 + 16 + l16) < V_COLS;
        #pragma unroll
        for (int mf = 0; mf < 4; ++mf) {
            #pragma unroll
            for (int r = 0; r < 4; ++r) {
                float mx = -INFINITY;
                if (v0) mx = acc[mf][0][r];
                if (v1) mx = fmaxf(mx, acc[mf][1][r]);
                #pragma unroll
                for (int d = 1; d < 16; d <<= 1) mx = fmaxf(mx, __shfl_xor(mx, d, 16));
                float s = 0.f;
                if (v0) s += __expf(acc[mf][0][r] - mx);
                if (v1) s += __expf(acc[mf][1][r] - mx);
                #pragma unroll
                for (int d = 1; d < 16; d <<= 1) s += __shfl_xor(s, d, 16);
                if (l16 == 0) stats[wn][wm * 64 + mf * 16 + q * 4 + r] = make_float2(mx, s);
            }
        }
        __syncthreads();
        if (tid < 128) {
            float2 p0 = stats[0][tid], p1 = stats[1][tid], p2 = stats[2][tid], p3 = stats[3][tid];
            float mm = fmaxf(fmaxf(p0.x, p1.x), fmaxf(p2.x, p3.x));
            float ss = p0.y * __expf(p0.x - mm) + p1.y * __expf(p1.x - mm)
                     + p2.y * __expf(p2.x - mm) + p3.y * __expf(p3.x - mm);
            partials[(long)(mbase + tid) * NNB + blockIdx.y] = make_float2(mm, ss);
        }
    } else {
        // ---- write scores - lse; LDS roundtrip for coalesced 512B/row segments
        __syncthreads();                        // tiles dead; reuse smem as score buffer
        float* sbuf = (float*)smem;             // stride 132 floats/row (2-way-free banks)
        #pragma unroll
        for (int mf = 0; mf < 4; ++mf)
            #pragma unroll
            for (int nf = 0; nf < 2; ++nf)
                #pragma unroll
                for (int r = 0; r < 4; ++r)
                    sbuf[(wm * 64 + mf * 16 + q * 4 + r) * 132 + wn * 32 + nf * 16 + l16] = acc[mf][nf][r];
        __syncthreads();
        #pragma unroll 4
        for (int it = 0; it < 32; ++it) {
            int i = it * 512 + tid;
            int r = i >> 7, c = i & 127;
            int col = nbase + c;
            if (col < V_COLS)
                __builtin_nontemporal_store(sbuf[r * 132 + c] - lsev[r],
                                            &out[(size_t)(mbase + r) * V_COLS + col]);
        }
    }
}

// ---------------------------------------------------------------- merge per-block (m,s) partials -> lse[b]
__global__ void merge_lse_kernel(const float2* __restrict__ partials, float* __restrict__ lse) {
    int b = blockIdx.x;
    int tid = threadIdx.x;
    float m = -INFINITY, s = 0.f;
    for (int i = tid; i < NNB; i += 256) {
        float2 p = partials[(long)b * NNB + i];
        if (p.x > m) { s = s * __expf(m - p.x) + p.y; m = p.x; }
        else         { s += p.y * __expf(p.x - m); }
    }
    __shared__ float sm[256], ss[256];
    sm[tid] = m; ss[tid] = s;
    __syncthreads();
    for (int off = 128; off > 0; off >>= 1) {
        if (tid < off) {
            float m1 = sm[tid], s1 = ss[tid];
            float m2 = sm[tid + off], s2 = ss[tid + off];
            float mm = fmaxf(m1, m2);
            sm[tid] = mm;
            ss[tid] = s1 * __expf(m1 - mm) + s2 * __expf(m2 - mm);
        }
        __syncthreads();
    }
    if (tid == 0) lse[b] = sm[0] + __logf(ss[0]);
}

// ---------------------------------------------------------------- launch
extern "C" void kernel_launch(void* const* d_in, const int* in_sizes, int n_in,
                              void* d_out, int out_size, void* d_ws, size_t ws_size,
                              hipStream_t stream) {
    const float* xs     = (const float*)d_in[0];
    const float* metric = (const float*)d_in[1];
    const float* EMB    = (const float*)d_in[2];
    const float* NEG    = (const float*)d_in[3];
    float* out = (float*)d_out;

    char* ws = (char*)d_ws;
    // layout: idx[1024] | t bf16[1024*128] | neg bf16[VPAD*128] | partials float2[1024*NNB] | lse[1024]
    int*            idx      = (int*)ws;                               // 4096 B
    unsigned short* t        = (unsigned short*)(ws + 4096);           // 262144 B -> 266240
    unsigned short* neg16    = (unsigned short*)(ws + 266240);         // VPAD*128*2 = 12877824 -> 13144064
    float2*         partials = (float2*)(ws + 13144064);               // 1024*393*8 = 3219456 -> 16363520
    float*          lse      = (float*)(ws + 16363520);                // 4096 B

    {
        long n4 = (long)B_ROWS * V_COLS / 4;
        int blocks = (int)((n4 + 255) / 256);
        find_idx_kernel<<<blocks, 256, 0, stream>>>(xs, idx);
    }
    cvt_bf16_kernel<<<(N4P + 255) / 256, 256, 0, stream>>>(NEG, (ushort4*)neg16);
    compute_t_kernel<<<B_ROWS, E_DIM, 0, stream>>>(EMB, metric, idx, t);
    gemm_kernel<false><<<dim3(B_ROWS / BM, NNB), 512, 0, stream>>>(t, neg16, partials, nullptr, nullptr);
    merge_lse_kernel<<<B_ROWS, 256, 0, stream>>>(partials, lse);
    gemm_kernel<true><<<dim3(B_ROWS / BM, NNB), 512, 0, stream>>>(t, neg16, partials, lse, out);
}

// Round 3
// 456.048 us; speedup vs baseline: 1.0399x; 1.0399x over previous
//
#include <hip/hip_runtime.h>
#include <hip/hip_bf16.h>
#include <math.h>

#define B_ROWS 1024
#define V_COLS 50257
#define E_DIM  128
#define BM     128
#define BN     128
#define NNB    393                 // ceil(V_COLS / BN)
#define VPAD   (NNB * BN)          // 50304
#define N4     (V_COLS * E_DIM / 4)   // 1608224
#define N4P    (VPAD * E_DIM / 4)     // 1609728

typedef __attribute__((ext_vector_type(8))) short short8;
typedef __attribute__((ext_vector_type(4))) float floatx4;

static __device__ __forceinline__ unsigned short f2bf(float x) {
    union { float f; unsigned int u; } c; c.f = x;
    unsigned int u = c.u;
    unsigned int r = u + 0x7fffu + ((u >> 16) & 1u);
    return (unsigned short)(r >> 16);
}

// async global->LDS, 16B per lane; LDS dest = uniform base + lane*16 (linear),
// swizzle applied on the per-lane GLOBAL address (m104/m173 pattern).
static __device__ __forceinline__ void gload16(const void* g, void* l) {
    __builtin_amdgcn_global_load_lds(
        (const __attribute__((address_space(1))) void*)g,
        (__attribute__((address_space(3))) void*)l,
        16, 0, 0);
}

// ---------------------------------------------------------------- find one-hot index
__global__ void find_idx_kernel(const float* __restrict__ xs, int* __restrict__ idx) {
    long i = (long)blockIdx.x * blockDim.x + threadIdx.x;
    const long n4 = (long)B_ROWS * V_COLS / 4;
    if (i >= n4) return;
    floatx4 v = __builtin_nontemporal_load((const floatx4*)xs + i);
    float vals[4] = {v.x, v.y, v.z, v.w};
    #pragma unroll
    for (int c = 0; c < 4; ++c) {
        if (vals[c] != 0.0f) {
            long f = 4 * i + c;
            int b = (int)(f / V_COLS);
            idx[b] = (int)(f - (long)b * V_COLS);
        }
    }
}

// ---------------------------------------------------------------- NEG fp32 -> bf16 (padded to VPAD rows, zeros)
__global__ void cvt_bf16_kernel(const float* __restrict__ src, ushort4* __restrict__ dst) {
    int i = blockIdx.x * blockDim.x + threadIdx.x;
    if (i >= N4P) return;
    ushort4 o;
    if (i < N4) {
        floatx4 v = __builtin_nontemporal_load((const floatx4*)src + i);
        o.x = f2bf(v.x); o.y = f2bf(v.y); o.z = f2bf(v.z); o.w = f2bf(v.w);
    } else {
        o.x = 0; o.y = 0; o.z = 0; o.w = 0;
    }
    dst[i] = o;
}

// ---------------------------------------------------------------- t[b] = EMBEDM[idx[b]] @ metric  (bf16 out)
__global__ void compute_t_kernel(const float* __restrict__ EMB, const float* __restrict__ metric,
                                 const int* __restrict__ idx, unsigned short* __restrict__ t) {
    __shared__ float erow[E_DIM];
    int b = blockIdx.x, tid = threadIdx.x;
    int id = idx[b];
    erow[tid] = EMB[(long)id * E_DIM + tid];
    __syncthreads();
    float acc = 0.f;
    #pragma unroll 16
    for (int k = 0; k < E_DIM; ++k) acc += erow[k] * metric[k * E_DIM + tid];
    t[b * E_DIM + tid] = f2bf(acc);
}

// ---------------------------------------------------------------- SINGLE-PASS tiled MFMA GEMM:
// scores = t @ neg^T ; writes RAW scores to out AND per-block (max,sumexp) partials.
// 128x128 tile, 512 threads = 8 waves (2x4). global_load_lds staging, source-swizzled.
__global__ __launch_bounds__(512, 4) void gemm_score_kernel(const unsigned short* __restrict__ t,
                                                            const unsigned short* __restrict__ neg,
                                                            float2* __restrict__ partials,
                                                            float* __restrict__ out) {
    __shared__ __align__(16) unsigned char smem[128 * 132 * 4]; // tiles (64KB), then score buf
    __shared__ float2 stats[4][128];

    const int tid  = threadIdx.x;
    const int lane = tid & 63, wave = tid >> 6;
    const int l16  = lane & 15, q = lane >> 4;
    const int wm   = wave >> 2, wn = wave & 3;          // 2 x 4 wave grid, each wave 64x32
    const int mbase = blockIdx.x * BM;
    const int nbase = blockIdx.y * BN;

    // ---- stage A (t rows) and B (neg rows) into LDS via async DMA
    uint4* ldsA = (uint4*)smem;
    uint4* ldsB = (uint4*)(smem + 32768);
    const uint4* srcA = (const uint4*)(t + (size_t)mbase * E_DIM);
    const uint4* srcB = (const uint4*)(neg + (size_t)nbase * E_DIM);
    {
        const int p0 = wave * 256 + lane;
        #pragma unroll
        for (int i = 0; i < 4; ++i) {
            int p = p0 + i * 64;
            int r = p >> 4, c = p & 15;
            int s = (r << 4) + (c ^ (r & 15));       // pre-swizzled global chunk
            int pbase = wave * 256 + i * 64;          // wave-uniform LDS chunk base
            gload16(srcA + s, ldsA + pbase);
            gload16(srcB + s, ldsB + pbase);
        }
    }
    __syncthreads();

    // ---- MFMA: each wave computes 64x32 (4x2 frags of 16x16x32)
    floatx4 acc[4][2];
    #pragma unroll
    for (int i = 0; i < 4; ++i)
        #pragma unroll
        for (int j = 0; j < 2; ++j) acc[i][j] = (floatx4){0, 0, 0, 0};

    #pragma unroll
    for (int ks = 0; ks < 4; ++ks) {
        short8 af[4], bfr[2];
        #pragma unroll
        for (int mf = 0; mf < 4; ++mf) {
            int row = wm * 64 + mf * 16 + l16;
            af[mf] = *(const short8*)&ldsA[(row << 4) + ((ks * 4 + q) ^ (row & 15))];
        }
        #pragma unroll
        for (int nf = 0; nf < 2; ++nf) {
            int row = wn * 32 + nf * 16 + l16;
            bfr[nf] = *(const short8*)&ldsB[(row << 4) + ((ks * 4 + q) ^ (row & 15))];
        }
        #pragma unroll
        for (int mf = 0; mf < 4; ++mf)
            #pragma unroll
            for (int nf = 0; nf < 2; ++nf)
                acc[mf][nf] = __builtin_amdgcn_mfma_f32_16x16x32_bf16(af[mf], bfr[nf], acc[mf][nf], 0, 0, 0);
    }

    // acc[mf][nf][r]: row = wm*64+mf*16+q*4+r, col = nbase+wn*32+nf*16+l16

    // ---- per-row (max, sumexp) over this block's 128 cols (registers + shfl only)
    const bool v0 = (nbase + wn * 32 + l16) < V_COLS;
    const bool v1 = (nbase + wn * 32 + 16 + l16) < V_COLS;
    #pragma unroll
    for (int mf = 0; mf < 4; ++mf) {
        #pragma unroll
        for (int r = 0; r < 4; ++r) {
            float mx = -INFINITY;
            if (v0) mx = acc[mf][0][r];
            if (v1) mx = fmaxf(mx, acc[mf][1][r]);
            #pragma unroll
            for (int d = 1; d < 16; d <<= 1) mx = fmaxf(mx, __shfl_xor(mx, d, 16));
            float s = 0.f;
            if (v0) s += __expf(acc[mf][0][r] - mx);
            if (v1) s += __expf(acc[mf][1][r] - mx);
            #pragma unroll
            for (int d = 1; d < 16; d <<= 1) s += __shfl_xor(s, d, 16);
            if (l16 == 0) stats[wn][wm * 64 + mf * 16 + q * 4 + r] = make_float2(mx, s);
        }
    }
    __syncthreads();   // stats visible; tiles dead (all MFMA ds_reads done)

    if (tid < 128) {
        float2 p0 = stats[0][tid], p1 = stats[1][tid], p2 = stats[2][tid], p3 = stats[3][tid];
        float mm = fmaxf(fmaxf(p0.x, p1.x), fmaxf(p2.x, p3.x));
        float ss = p0.y * __expf(p0.x - mm) + p1.y * __expf(p1.x - mm)
                 + p2.y * __expf(p2.x - mm) + p3.y * __expf(p3.x - mm);
        partials[(long)(mbase + tid) * NNB + blockIdx.y] = make_float2(mm, ss);
    }

    // ---- write RAW scores via LDS roundtrip for coalesced 512B/row segments
    float* sbuf = (float*)smem;             // stride 132 floats/row
    #pragma unroll
    for (int mf = 0; mf < 4; ++mf)
        #pragma unroll
        for (int nf = 0; nf < 2; ++nf)
            #pragma unroll
            for (int r = 0; r < 4; ++r)
                sbuf[(wm * 64 + mf * 16 + q * 4 + r) * 132 + wn * 32 + nf * 16 + l16] = acc[mf][nf][r];
    __syncthreads();
    #pragma unroll 4
    for (int it = 0; it < 32; ++it) {
        int i = it * 512 + tid;
        int r = i >> 7, c = i & 127;
        int col = nbase + c;
        if (col < V_COLS)
            out[(size_t)(mbase + r) * V_COLS + col] = sbuf[r * 132 + c];
    }
}

// ---------------------------------------------------------------- merge partials -> lse[b], then out[b,:] -= lse
__global__ __launch_bounds__(512) void merge_sub_kernel(const float2* __restrict__ partials,
                                                        float* __restrict__ out) {
    int b = blockIdx.x;
    int tid = threadIdx.x;
    float m = -INFINITY, s = 0.f;
    for (int i = tid; i < NNB; i += 512) {
        float2 p = partials[(long)b * NNB + i];
        if (p.x > m) { s = s * __expf(m - p.x) + p.y; m = p.x; }
        else         { s += p.y * __expf(p.x - m); }
    }
    __shared__ float sm[512], ss[512];
    sm[tid] = m; ss[tid] = s;
    __syncthreads();
    for (int off = 256; off > 0; off >>= 1) {
        if (tid < off) {
            float m1 = sm[tid], s1 = ss[tid];
            float m2 = sm[tid + off], s2 = ss[tid + off];
            float mm = fmaxf(m1, m2);
            sm[tid] = mm;
            ss[tid] = s1 * __expf(m1 - mm) + s2 * __expf(m2 - mm);
        }
        __syncthreads();
    }
    __shared__ float lse_sh;
    if (tid == 0) lse_sh = sm[0] + __logf(ss[0]);
    __syncthreads();
    const float l = lse_sh;

    // ---- stream row b in place: head scalars to 16B alignment, float4 body, tail scalars
    float* p = out + (size_t)b * V_COLS;
    int mis  = (int)(((unsigned long long)(uintptr_t)p >> 2) & 3ull);
    int head = (4 - mis) & 3;
    if (tid < head) p[tid] -= l;
    int n4 = (V_COLS - head) >> 2;
    floatx4* p4 = (floatx4*)(p + head);
    for (int i = tid; i < n4; i += 512) {
        floatx4 v = p4[i];
        v -= l;
        p4[i] = v;
    }
    int done = head + (n4 << 2);
    if (tid < V_COLS - done) p[done + tid] -= l;
}

// ---------------------------------------------------------------- launch
extern "C" void kernel_launch(void* const* d_in, const int* in_sizes, int n_in,
                              void* d_out, int out_size, void* d_ws, size_t ws_size,
                              hipStream_t stream) {
    const float* xs     = (const float*)d_in[0];
    const float* metric = (const float*)d_in[1];
    const float* EMB    = (const float*)d_in[2];
    const float* NEG    = (const float*)d_in[3];
    float* out = (float*)d_out;

    char* ws = (char*)d_ws;
    // layout: idx[1024] | t bf16[1024*128] | neg bf16[VPAD*128] | partials float2[1024*NNB]
    int*            idx      = (int*)ws;                               // 4096 B
    unsigned short* t        = (unsigned short*)(ws + 4096);           // 262144 B -> 266240
    unsigned short* neg16    = (unsigned short*)(ws + 266240);         // VPAD*128*2 = 12877824 -> 13144064
    float2*         partials = (float2*)(ws + 13144064);               // 1024*393*8 = 3219456 -> 16363520

    {
        long n4 = (long)B_ROWS * V_COLS / 4;
        int blocks = (int)((n4 + 255) / 256);
        find_idx_kernel<<<blocks, 256, 0, stream>>>(xs, idx);
    }
    cvt_bf16_kernel<<<(N4P + 255) / 256, 256, 0, stream>>>(NEG, (ushort4*)neg16);
    compute_t_kernel<<<B_ROWS, E_DIM, 0, stream>>>(EMB, metric, idx, t);
    gemm_score_kernel<<<dim3(B_ROWS / BM, NNB), 512, 0, stream>>>(t, neg16, partials, out);
    merge_sub_kernel<<<B_ROWS, 512, 0, stream>>>(partials, out);
}

// Round 5
// 438.518 us; speedup vs baseline: 1.0814x; 1.0400x over previous
//
#include <hip/hip_runtime.h>
#include <hip/hip_bf16.h>
#include <math.h>

#define B_ROWS 1024
#define V_COLS 50257
#define E_DIM  128
#define BM     128
#define BN     128
#define NNB    393                 // ceil(V_COLS / BN)
#define VPAD   (NNB * BN)          // 50304
#define N4     (V_COLS * E_DIM / 4)   // 1608224
#define N4P    (VPAD * E_DIM / 4)     // 1609728
#define NCHUNK 32                  // N-tile chunks per m-panel; grid = 8*32 = 256 blocks

typedef __attribute__((ext_vector_type(8))) short short8;
typedef __attribute__((ext_vector_type(4))) float floatx4;

static __device__ __forceinline__ unsigned short f2bf(float x) {
    union { float f; unsigned int u; } c; c.f = x;
    unsigned int u = c.u;
    unsigned int r = u + 0x7fffu + ((u >> 16) & 1u);
    return (unsigned short)(r >> 16);
}

// async global->LDS, 16B per lane; LDS dest = wave-uniform base + lane*16 (linear),
// swizzle applied on the per-lane GLOBAL address (m104/m173 pattern).
static __device__ __forceinline__ void gload16(const void* g, void* l) {
    __builtin_amdgcn_global_load_lds(
        (const __attribute__((address_space(1))) void*)g,
        (__attribute__((address_space(3))) void*)l,
        16, 0, 0);
}

// ---------------------------------------------------------------- find one-hot index
__global__ void find_idx_kernel(const float* __restrict__ xs, int* __restrict__ idx) {
    long i = (long)blockIdx.x * blockDim.x + threadIdx.x;
    const long n4 = (long)B_ROWS * V_COLS / 4;
    if (i >= n4) return;
    floatx4 v = __builtin_nontemporal_load((const floatx4*)xs + i);
    float vals[4] = {v.x, v.y, v.z, v.w};
    #pragma unroll
    for (int c = 0; c < 4; ++c) {
        if (vals[c] != 0.0f) {
            long f = 4 * i + c;
            int b = (int)(f / V_COLS);
            idx[b] = (int)(f - (long)b * V_COLS);
        }
    }
}

// ---------------------------------------------------------------- NEG fp32 -> bf16 (padded to VPAD rows, zeros)
__global__ void cvt_bf16_kernel(const float* __restrict__ src, ushort4* __restrict__ dst) {
    int i = blockIdx.x * blockDim.x + threadIdx.x;
    if (i >= N4P) return;
    ushort4 o;
    if (i < N4) {
        floatx4 v = __builtin_nontemporal_load((const floatx4*)src + i);
        o.x = f2bf(v.x); o.y = f2bf(v.y); o.z = f2bf(v.z); o.w = f2bf(v.w);
    } else {
        o.x = 0; o.y = 0; o.z = 0; o.w = 0;
    }
    dst[i] = o;
}

// ---------------------------------------------------------------- t[b] = EMBEDM[idx[b]] @ metric  (bf16 out)
__global__ void compute_t_kernel(const float* __restrict__ EMB, const float* __restrict__ metric,
                                 const int* __restrict__ idx, unsigned short* __restrict__ t) {
    __shared__ float erow[E_DIM];
    int b = blockIdx.x, tid = threadIdx.x;
    int id = idx[b];
    erow[tid] = EMB[(long)id * E_DIM + tid];
    __syncthreads();
    float acc = 0.f;
    #pragma unroll 16
    for (int k = 0; k < E_DIM; ++k) acc += erow[k] * metric[k * E_DIM + tid];
    t[b * E_DIM + tid] = f2bf(acc);
}

// ---------------------------------------------------------------- chunked multi-tile MFMA GEMM
// 256 blocks (1/CU), 512 thr = 8 waves (2 wm x 4 wn). Block owns m-panel (128 rows) x ~13 N-tiles.
// A-frags in registers (from L2-hot t); B double-buffered in LDS via global_load_lds.
// Pass LSE (WRITE_OUT=0): online (max,sumexp) in regs across tiles -> partials[b][128].
// Pass OUT (WRITE_OUT=1): writes score - lse directly.
template <bool WRITE_OUT>
__global__ __launch_bounds__(512, 2) void gemm_chunk_kernel(const unsigned short* __restrict__ t,
                                                            const unsigned short* __restrict__ neg,
                                                            float2* __restrict__ partials,
                                                            const float* __restrict__ lse,
                                                            float* __restrict__ out) {
    __shared__ __align__(16) uint4 bbuf[2][2048];   // 2 x 32KB B tiles

    const int lin  = blockIdx.x;
    // XCD-chunk mapping: the 8 m-blocks sharing chunk c land on the same XCD (lin%8 == c%8)
    const int m    = (lin >> 3) & 7;
    const int c    = (lin & 7) | ((lin >> 6) << 3);
    const int t0   = (c * NNB) / NCHUNK;
    const int t1   = ((c + 1) * NNB) / NCHUNK;

    const int tid  = threadIdx.x;
    const int lane = tid & 63, wave = tid >> 6;
    const int l16  = lane & 15, q = lane >> 4;
    const int wm   = wave >> 2, wn = wave & 3;       // 2x4 wave grid; wave = 64 rows x 32 cols
    const int mbase = m * BM;

    // ---- A fragments in registers: af[mf][ks], row = mbase+wm*64+mf*16+l16, k = ks*32+q*8
    short8 af[4][4];
    #pragma unroll
    for (int mf = 0; mf < 4; ++mf)
        #pragma unroll
        for (int ks = 0; ks < 4; ++ks)
            af[mf][ks] = *(const short8*)&t[(size_t)(mbase + wm * 64 + mf * 16 + l16) * E_DIM + ks * 32 + q * 8];

    // per-row state
    float lsev[4][4];      // WRITE_OUT: lse per (mf,r)
    float mrun[4][4], srun[4][4];
    if (WRITE_OUT) {
        #pragma unroll
        for (int mf = 0; mf < 4; ++mf)
            #pragma unroll
            for (int r = 0; r < 4; ++r)
                lsev[mf][r] = lse[mbase + wm * 64 + mf * 16 + q * 4 + r];
    } else {
        #pragma unroll
        for (int mf = 0; mf < 4; ++mf)
            #pragma unroll
            for (int r = 0; r < 4; ++r) { mrun[mf][r] = -INFINITY; srun[mf][r] = 0.f; }
    }

    // ---- staging helper: tile -> bbuf[buf] (2048 chunks of 16B, src-swizzled, LDS linear)
    const int p0 = wave * 256 + lane;
    auto STAGE = [&](int buf, int tile) {
        const uint4* srcB = (const uint4*)(neg + (size_t)tile * BN * E_DIM);
        #pragma unroll
        for (int i = 0; i < 4; ++i) {
            int p = p0 + i * 64;
            int r = p >> 4, cc = p & 15;
            int s = (r << 4) + (cc ^ (r & 15));
            gload16(srcB + s, &bbuf[buf][wave * 256 + i * 64]);
        }
    };

    STAGE(0, t0);
    __syncthreads();

    for (int tt = t0; tt < t1; ++tt) {
        const int cur = (tt - t0) & 1;
        if (tt + 1 < t1) STAGE(cur ^ 1, tt + 1);   // prefetch next while computing cur

        floatx4 acc[4][2];
        #pragma unroll
        for (int i = 0; i < 4; ++i)
            #pragma unroll
            for (int j = 0; j < 2; ++j) acc[i][j] = (floatx4){0, 0, 0, 0};

        #pragma unroll
        for (int ks = 0; ks < 4; ++ks) {
            short8 bfr[2];
            #pragma unroll
            for (int nf = 0; nf < 2; ++nf) {
                int row = wn * 32 + nf * 16 + l16;
                bfr[nf] = *(const short8*)&bbuf[cur][(row << 4) + ((ks * 4 + q) ^ (row & 15))];
            }
            #pragma unroll
            for (int mf = 0; mf < 4; ++mf)
                #pragma unroll
                for (int nf = 0; nf < 2; ++nf)
                    acc[mf][nf] = __builtin_amdgcn_mfma_f32_16x16x32_bf16(af[mf][ks], bfr[nf], acc[mf][nf], 0, 0, 0);
        }

        // acc[mf][nf][r]: row = mbase+wm*64+mf*16+q*4+r, col = tt*128 + wn*32 + nf*16 + l16
        const int col0 = tt * BN + wn * 32 + l16;
        const bool v0 = col0 < V_COLS;
        const bool v1 = (col0 + 16) < V_COLS;

        if (!WRITE_OUT) {
            #pragma unroll
            for (int mf = 0; mf < 4; ++mf)
                #pragma unroll
                for (int r = 0; r < 4; ++r) {
                    float a0 = v0 ? acc[mf][0][r] : -INFINITY;
                    float a1 = v1 ? acc[mf][1][r] : -INFINITY;
                    float nm = fmaxf(mrun[mf][r], fmaxf(a0, a1));
                    float s  = srun[mf][r] * __expf(mrun[mf][r] - nm);
                    if (v0) s += __expf(a0 - nm);
                    if (v1) s += __expf(a1 - nm);
                    mrun[mf][r] = nm; srun[mf][r] = s;
                }
        } else {
            #pragma unroll
            for (int mf = 0; mf < 4; ++mf) {
                const size_t rowb = (size_t)(mbase + wm * 64 + mf * 16 + q * 4) * V_COLS;
                #pragma unroll
                for (int r = 0; r < 4; ++r) {
                    if (v0) out[rowb + (size_t)r * V_COLS + col0]      = acc[mf][0][r] - lsev[mf][r];
                    if (v1) out[rowb + (size_t)r * V_COLS + col0 + 16] = acc[mf][1][r] - lsev[mf][r];
                }
            }
        }
        __syncthreads();   // everyone done with bbuf[cur]; prefetch into cur^1 drained
    }

    if (!WRITE_OUT) {
        // cross-lane merge over the 16 l16 lanes (same row, different cols)
        #pragma unroll
        for (int mf = 0; mf < 4; ++mf)
            #pragma unroll
            for (int r = 0; r < 4; ++r) {
                float mm = mrun[mf][r], ss = srun[mf][r];
                #pragma unroll
                for (int d = 1; d < 16; d <<= 1) {
                    float mo = __shfl_xor(mm, d, 16);
                    float so = __shfl_xor(ss, d, 16);
                    float nm = fmaxf(mm, mo);
                    ss = ss * __expf(mm - nm) + so * __expf(mo - nm);
                    mm = nm;
                }
                if (l16 == 0) {
                    int row_local = wm * 64 + mf * 16 + q * 4 + r;
                    partials[(((size_t)mbase + row_local) * NCHUNK + c) * 4 + wn] = make_float2(mm, ss);
                }
            }
    }
}

// ---------------------------------------------------------------- merge 128 partials/row -> lse[b]
__global__ __launch_bounds__(128) void merge_lse_kernel(const float2* __restrict__ partials,
                                                        float* __restrict__ lse) {
    int b = blockIdx.x, tid = threadIdx.x;
    float2 p = partials[(size_t)b * 128 + tid];
    float mm = p.x, ss = p.y;
    // reduce within each wave (64), then across the 2 waves via LDS
    #pragma unroll
    for (int d = 1; d < 64; d <<= 1) {
        float mo = __shfl_xor(mm, d, 64);
        float so = __shfl_xor(ss, d, 64);
        float nm = fmaxf(mm, mo);
        ss = ss * __expf(mm - nm) + so * __expf(mo - nm);
        mm = nm;
    }
    __shared__ float m2[2], s2[2];
    if ((tid & 63) == 0) { m2[tid >> 6] = mm; s2[tid >> 6] = ss; }
    __syncthreads();
    if (tid == 0) {
        float nm = fmaxf(m2[0], m2[1]);
        float s  = s2[0] * __expf(m2[0] - nm) + s2[1] * __expf(m2[1] - nm);
        lse[b] = nm + __logf(s);
    }
}

// ---------------------------------------------------------------- launch
extern "C" void kernel_launch(void* const* d_in, const int* in_sizes, int n_in,
                              void* d_out, int out_size, void* d_ws, size_t ws_size,
                              hipStream_t stream) {
    const float* xs     = (const float*)d_in[0];
    const float* metric = (const float*)d_in[1];
    const float* EMB    = (const float*)d_in[2];
    const float* NEG    = (const float*)d_in[3];
    float* out = (float*)d_out;

    char* ws = (char*)d_ws;
    // layout: idx[1024] | t bf16[1024*128] | neg bf16[VPAD*128] | partials float2[1024*128] | lse[1024]
    int*            idx      = (int*)ws;                               // 4096 B
    unsigned short* t        = (unsigned short*)(ws + 4096);           // 262144 -> 266240
    unsigned short* neg16    = (unsigned short*)(ws + 266240);         // 12877824 -> 13144064
    float2*         partials = (float2*)(ws + 13144064);               // 1024*128*8 = 1048576 -> 14192640
    float*          lse      = (float*)(ws + 14192640);                // 4096 B

    {
        long n4 = (long)B_ROWS * V_COLS / 4;
        int blocks = (int)((n4 + 255) / 256);
        find_idx_kernel<<<blocks, 256, 0, stream>>>(xs, idx);
    }
    cvt_bf16_kernel<<<(N4P + 255) / 256, 256, 0, stream>>>(NEG, (ushort4*)neg16);
    compute_t_kernel<<<B_ROWS, E_DIM, 0, stream>>>(EMB, metric, idx, t);
    gemm_chunk_kernel<false><<<8 * NCHUNK, 512, 0, stream>>>(t, neg16, partials, nullptr, nullptr);
    merge_lse_kernel<<<B_ROWS, 128, 0, stream>>>(partials, lse);
    gemm_chunk_kernel<true><<<8 * NCHUNK, 512, 0, stream>>>(t, neg16, partials, lse, out);
}